// Round 8
// baseline (3236.985 us; speedup 1.0000x reference)
//
#include <hip/hip_runtime.h>
#include <stdint.h>

typedef _Float16 half8 __attribute__((ext_vector_type(8)));  // 8 fp16 (4 VGPR) MFMA frag
typedef __attribute__((ext_vector_type(4))) float f4;        // fp32x4 accum
typedef __attribute__((ext_vector_type(4))) unsigned int u32x4;
typedef __attribute__((ext_vector_type(2))) unsigned int u32x2;

#define LDA1 1160  // halves per LDS A row: 1152 data (576 hi | 576 lo) + 8 pad; 580 words ≡ 4 mod 32 -> 2-way (free)
#define EXS  36    // exchange stride (floats); 144B row, 16B-aligned f4 reads, 2-way max
#define HSTR 40    // sH stride (halves), 80B: 16B-aligned, 2-way max

__device__ __forceinline__ float sigm(float x) { return 1.0f / (1.0f + __expf(-x)); }
__device__ __forceinline__ float tanh_(float x) { return 1.0f - 2.0f / (__expf(2.0f * x) + 1.0f); } // overflow-safe

// ---------------- prologue kernels ----------------

// W_catA[2048][576] = [W_ih | W_hh] fp16 ; also W_ih part of W_catB
extern "C" __global__ void __launch_bounds__(256) k_wcat(
    const float* __restrict__ Wih, const float* __restrict__ Whh,
    _Float16* __restrict__ WA, _Float16* __restrict__ WB)
{
    int idx = blockIdx.x * 256 + threadIdx.x;        // grid 4608 -> exactly 2048*576
    int n = idx / 576, k = idx % 576;
    float v = (k < 64) ? Wih[n * 64 + k] : Whh[n * 512 + (k - 64)];
    _Float16 b = (_Float16)v;
    WA[idx] = b;
    if (k < 64) WB[idx] = b;
}

// W_catB[n][64+k] = W_hh[n][k] + sum_p W_ih[n][p] * W_out[p][k]   (fp32 accum, fp16 store)
extern "C" __global__ void __launch_bounds__(256) k_comb(
    const float* __restrict__ Wih, const float* __restrict__ Whh,
    const float* __restrict__ Wo, _Float16* __restrict__ WB)
{
    int bx = blockIdx.x;                             // grid 4096
    int n = bx >> 1;
    int kh = ((bx & 1) << 8) + threadIdx.x;          // 0..511
    float acc = Whh[n * 512 + kh];
    #pragma unroll 16
    for (int p = 0; p < 64; ++p)
        acc += Wih[n * 64 + p] * Wo[p * 512 + kh];
    WB[n * 576 + 64 + kh] = (_Float16)acc;
}

// Wout fp16, bias0 = b_ih+b_hh, bias1 = bias0 + W_ih@b_out, y_{-1} init (fp32 + fp16 hi/lo, both parities)
extern "C" __global__ void __launch_bounds__(256) k_misc(
    const float* __restrict__ Wo, const float* __restrict__ bih, const float* __restrict__ bhh,
    const float* __restrict__ Wih, const float* __restrict__ bo, const float* __restrict__ x,
    _Float16* __restrict__ WoB, float* __restrict__ b0v, float* __restrict__ b1v,
    float* __restrict__ yf0, float* __restrict__ yf1,
    _Float16* __restrict__ yh0, _Float16* __restrict__ yh1,
    _Float16* __restrict__ yl0, _Float16* __restrict__ yl1)
{
    int idx = blockIdx.x * 256 + threadIdx.x;        // grid 392
    if (idx < 32768) { WoB[idx] = (_Float16)Wo[idx]; return; }
    if (idx < 34816) {
        int n = idx - 32768;
        float b = bih[n] + bhh[n];
        b0v[n] = b;
        float a = b;
        #pragma unroll 16
        for (int p = 0; p < 64; ++p) a += Wih[n * 64 + p] * bo[p];
        b1v[n] = a;
        return;
    }
    if (idx < 100352) {
        int e = idx - 34816;
        int m = e >> 6, nn = e & 63;
        float v = x[m * 2048 + 31 * 64 + nn];        // x[:, -1, :]
        yf0[e] = v; yf1[e] = v;
        _Float16 hi = (_Float16)v;
        _Float16 lo = (_Float16)(v - (float)hi);
        yh0[e] = hi; yh1[e] = hi;
        yl0[e] = lo; yl1[e] = lo;
    }
}

// h0 = z @ Wproj^T + b_proj ; c0 = h0 ; h stored fp16 hi/lo
extern "C" __global__ void __launch_bounds__(256) k_h0(
    const float* __restrict__ z, const float* __restrict__ Wp, const float* __restrict__ bp,
    float* __restrict__ cst, _Float16* __restrict__ hh0, _Float16* __restrict__ hl0)
{
    int bx = blockIdx.x;                             // grid 2048
    int m = bx >> 1;
    int n = ((bx & 1) << 8) + threadIdx.x;
    float acc = bp[n];
    const f4* zr = (const f4*)&z[m * 128];           // block-uniform (scalar loads)
    const f4* wr = (const f4*)&Wp[n * 128];
    #pragma unroll 8
    for (int p = 0; p < 32; ++p) {
        f4 zv = zr[p], wv = wr[p];
        acc += zv[0]*wv[0] + zv[1]*wv[1] + zv[2]*wv[2] + zv[3]*wv[3];
    }
    cst[m * 512 + n] = acc;
    _Float16 hi = (_Float16)acc;
    hh0[m * 512 + n] = hi;
    hl0[m * 512 + n] = (_Float16)(acc - (float)hi);
}

// ---------------- per-step kernel ----------------
// grid 256 = 16 mt x 16 s, 256 thr, 1 block/CU (LDS 158.7 KB). SINGLE-STAGE schedule:
// R2's chunked loop serialized staging (compiler emits s_waitcnt vmcnt(0) before every
// s_barrier -> the "T14 prefetch" was drained before each MFMA phase; 9 barriers/step).
// Here: whole A (64 x 1152 halves, hi|lo) staged once -> ONE drain+barrier -> 18 K-iters
// of uninterrupted MFMA (B rolling-prefetched 3-deep from L2) -> 3 cheap barriers for
// exchange/cell/delta. y-resolve loads issue FIRST and complete under the stage drain.
// A col g (0..575): g<64 -> y[g], else h[g-64]; B col = g for BOTH hi and lo A halves.
// t in [0,128]; t==128 -> resolution of y_127 only.

__device__ __forceinline__ void resolve_fin(
    int t, int row, int c4, f4 a,
    float* __restrict__ yf_out,
    _Float16* __restrict__ yh_out, _Float16* __restrict__ yl_out,
    float* __restrict__ out)
{
    *(f4*)&yf_out[row * 64 + c4] = a;
    *(f4*)&out[row * 8192 + (t - 1) * 64 + c4] = a;
    _Float16 hi4[4], lo4[4];
    #pragma unroll
    for (int x = 0; x < 4; ++x) {
        hi4[x] = (_Float16)a[x];
        lo4[x] = (_Float16)(a[x] - (float)hi4[x]);
    }
    *(u32x2*)&yh_out[row * 64 + c4] = *(u32x2*)hi4;
    *(u32x2*)&yl_out[row * 64 + c4] = *(u32x2*)lo4;
}

extern "C" __global__ void __launch_bounds__(256, 1) k_step(
    int t,
    const _Float16* __restrict__ Wcat,         // [2048][576] fp16 (A or B variant)
    const float* __restrict__ bias,            // [2048]
    const _Float16* __restrict__ Wout,         // [64][512] fp16
    const float* __restrict__ bout,            // [64]
    const _Float16* __restrict__ hh_in, const _Float16* __restrict__ hl_in,  // [1024][512]
    _Float16* __restrict__ hh_out, _Float16* __restrict__ hl_out,
    float* __restrict__ cst,                   // [1024][512] fp32 (in-place)
    const float* __restrict__ yf_in, float* __restrict__ yf_out,             // [1024][64]
    const _Float16* __restrict__ yh_in, _Float16* __restrict__ yh_out,
    const _Float16* __restrict__ yl_in, _Float16* __restrict__ yl_out,
    const float* __restrict__ dl_in, float* __restrict__ dl_out,             // [16][1024][64]
    float* __restrict__ out)                   // [1024][128][64]
{
    __shared__ __align__(16) unsigned char smem[158720];
    _Float16* sA  = (_Float16*)smem;                             // [64][LDA1] = 148,480 B
    float*    sEx = (float*)smem;                                // overlay: [4][64][EXS] = 36,864 B
    _Float16* sHh = (_Float16*)(smem + 148480);                  // [64][HSTR] = 5,120 B
    _Float16* sHl = (_Float16*)(smem + 153600);                  // 5,120 B (ends 158,720)

    const int tid = threadIdx.x;
    const int bx  = blockIdx.x;
    const int mt  = bx >> 4, s = bx & 15;
    const int m0  = mt * 64, j0 = s * 32;

    if (t >= 128) {                                  // final launch: resolve y_127 only
        if (tid < 64) {
            int row = m0 + s * 4 + (tid >> 4);
            int c4  = (tid & 15) * 4;
            f4 a = *(const f4*)&yf_in[row * 64 + c4];
            a += *(const f4*)&bout[c4];
            #pragma unroll
            for (int sp = 0; sp < 16; ++sp)
                a += *(const f4*)&dl_in[sp * 65536 + row * 64 + c4];
            resolve_fin(t, row, c4, a, yf_out, yh_out, yl_out, out);
        }
        return;
    }

    const int wv = tid >> 6, lane = tid & 63, l15 = lane & 15, quad = lane >> 4;
    const int quad8 = quad * 8;

    // ---- resolve y_{t-1}: issue loads FIRST (latency hides under staging) ----
    const bool dores = (t >= 1) && (tid < 64);
    const int rrow = m0 + s * 4 + (tid >> 4);
    const int rc4  = (tid & 15) * 4;
    f4 ry = {0.0f, 0.0f, 0.0f, 0.0f}, rbo = ry;
    f4 rdl[16];
    if (dores) {
        ry  = *(const f4*)&yf_in[rrow * 64 + rc4];
        rbo = *(const f4*)&bout[rc4];
        #pragma unroll
        for (int sp = 0; sp < 16; ++sp)
            rdl[sp] = *(const f4*)&dl_in[sp * 65536 + rrow * 64 + rc4];
    }

    // ---- head prefetches (consumed post-GEMM) ----
    const int cm = tid >> 2, cjb = (tid & 3) * 8;    // cell: row cm, 8 cols at cjb
    const int cjcol = j0 + cjb;
    const int ccrow = (m0 + cm) * 512 + cjcol;
    f4 cpre0 = *(const f4*)&cst[ccrow];
    f4 cpre1 = *(const f4*)&cst[ccrow + 4];
    f4 bi[8];                                        // [2*gate + half4]
    #pragma unroll
    for (int g = 0; g < 4; ++g) {
        bi[2*g]   = *(const f4*)&bias[g * 512 + cjcol];
        bi[2*g+1] = *(const f4*)&bias[g * 512 + cjcol + 4];
    }
    half8 bw = *(const half8*)&Wout[(wv * 16 + l15) * 512 + j0 + quad8];

    const int brow0 = (wv * 512 + j0 + l15) * 576;
    const int brow1 = (wv * 512 + j0 + 16 + l15) * 576;

    // ---- B rolling prefetch, depth 3 ----
    half8 bv0[3], bv1[3];
    #pragma unroll
    for (int p = 0; p < 3; ++p) {
        bv0[p] = *(const half8*)&Wcat[brow0 + p * 32 + quad8];
        bv1[p] = *(const half8*)&Wcat[brow1 + p * 32 + quad8];
    }

    // ---- single-stage ALL of A: 36 x 16B per thread (64 rows x 1152 halves) ----
    #pragma unroll
    for (int it = 0; it < 36; ++it) {
        int i4 = it * 256 + tid;                     // 0..9215
        int r  = i4 / 144;
        int cc = (i4 % 144) * 8;                     // 0..1144
        const _Float16* src;
        if (cc < 64)        src = &yh_in[(m0 + r) * 64 + cc];
        else if (cc < 576)  src = &hh_in[(m0 + r) * 512 + (cc - 64)];
        else if (cc < 640)  src = &yl_in[(m0 + r) * 64 + (cc - 576)];
        else                src = &hl_in[(m0 + r) * 512 + (cc - 640)];
        *(u32x4*)&sA[r * LDA1 + cc] = *(const u32x4*)src;
    }

    // ---- resolve finish: its loads completed under the staging phase ----
    if (dores) {
        f4 a = ry + rbo;
        #pragma unroll
        for (int sp = 0; sp < 16; ++sp) a += rdl[sp];
        resolve_fin(t, rrow, rc4, a, yf_out, yh_out, yl_out, out);
    }

    f4 zero = {0.0f, 0.0f, 0.0f, 0.0f};
    f4 acc[4][2];
    #pragma unroll
    for (int a = 0; a < 4; ++a) { acc[a][0] = zero; acc[a][1] = zero; }

    __syncthreads();                                 // the ONE staged-data barrier

    // ---- 18 uninterrupted K-iterations: 16 MFMA each, B prefetched 3 ahead ----
    #pragma unroll
    for (int kc = 0; kc < 18; ++kc) {
        half8 b0 = bv0[kc % 3], b1 = bv1[kc % 3];
        if (kc < 15) {
            bv0[kc % 3] = *(const half8*)&Wcat[brow0 + (kc + 3) * 32 + quad8];
            bv1[kc % 3] = *(const half8*)&Wcat[brow1 + (kc + 3) * 32 + quad8];
        }
        int kq = kc * 32 + quad8;
        half8 ah0 = *(const half8*)&sA[(l15     ) * LDA1 + kq];
        half8 ah1 = *(const half8*)&sA[(l15 + 16) * LDA1 + kq];
        half8 ah2 = *(const half8*)&sA[(l15 + 32) * LDA1 + kq];
        half8 ah3 = *(const half8*)&sA[(l15 + 48) * LDA1 + kq];
        acc[0][0] = __builtin_amdgcn_mfma_f32_16x16x32_f16(ah0, b0, acc[0][0], 0, 0, 0);
        acc[1][0] = __builtin_amdgcn_mfma_f32_16x16x32_f16(ah1, b0, acc[1][0], 0, 0, 0);
        acc[2][0] = __builtin_amdgcn_mfma_f32_16x16x32_f16(ah2, b0, acc[2][0], 0, 0, 0);
        acc[3][0] = __builtin_amdgcn_mfma_f32_16x16x32_f16(ah3, b0, acc[3][0], 0, 0, 0);
        acc[0][1] = __builtin_amdgcn_mfma_f32_16x16x32_f16(ah0, b1, acc[0][1], 0, 0, 0);
        acc[1][1] = __builtin_amdgcn_mfma_f32_16x16x32_f16(ah1, b1, acc[1][1], 0, 0, 0);
        acc[2][1] = __builtin_amdgcn_mfma_f32_16x16x32_f16(ah2, b1, acc[2][1], 0, 0, 0);
        acc[3][1] = __builtin_amdgcn_mfma_f32_16x16x32_f16(ah3, b1, acc[3][1], 0, 0, 0);
        half8 al0 = *(const half8*)&sA[(l15     ) * LDA1 + 576 + kq];
        half8 al1 = *(const half8*)&sA[(l15 + 16) * LDA1 + 576 + kq];
        half8 al2 = *(const half8*)&sA[(l15 + 32) * LDA1 + 576 + kq];
        half8 al3 = *(const half8*)&sA[(l15 + 48) * LDA1 + 576 + kq];
        acc[0][0] = __builtin_amdgcn_mfma_f32_16x16x32_f16(al0, b0, acc[0][0], 0, 0, 0);
        acc[1][0] = __builtin_amdgcn_mfma_f32_16x16x32_f16(al1, b0, acc[1][0], 0, 0, 0);
        acc[2][0] = __builtin_amdgcn_mfma_f32_16x16x32_f16(al2, b0, acc[2][0], 0, 0, 0);
        acc[3][0] = __builtin_amdgcn_mfma_f32_16x16x32_f16(al3, b0, acc[3][0], 0, 0, 0);
        acc[0][1] = __builtin_amdgcn_mfma_f32_16x16x32_f16(al0, b1, acc[0][1], 0, 0, 0);
        acc[1][1] = __builtin_amdgcn_mfma_f32_16x16x32_f16(al1, b1, acc[1][1], 0, 0, 0);
        acc[2][1] = __builtin_amdgcn_mfma_f32_16x16x32_f16(al2, b1, acc[2][1], 0, 0, 0);
        acc[3][1] = __builtin_amdgcn_mfma_f32_16x16x32_f16(al3, b1, acc[3][1], 0, 0, 0);
    }
    __syncthreads();                                 // sA dead -> overlay exchange

    // ---- gate exchange: wave wv = quadrant wv. D layout: col=lane&15, row=quad*4+reg ----
    #pragma unroll
    for (int a = 0; a < 4; ++a)
        #pragma unroll
        for (int b = 0; b < 2; ++b)
            #pragma unroll
            for (int r = 0; r < 4; ++r)
                sEx[(wv * 64 + a * 16 + quad * 4 + r) * EXS + b * 16 + l15] = acc[a][b][r];
    __syncthreads();

    // ---- LSTM cell update: thread -> row cm, 8 h-cols at cjb ----
    {
        f4 gI0 = *(const f4*)&sEx[(0 * 64 + cm) * EXS + cjb];
        f4 gI1 = *(const f4*)&sEx[(0 * 64 + cm) * EXS + cjb + 4];
        f4 gF0 = *(const f4*)&sEx[(1 * 64 + cm) * EXS + cjb];
        f4 gF1 = *(const f4*)&sEx[(1 * 64 + cm) * EXS + cjb + 4];
        f4 gG0 = *(const f4*)&sEx[(2 * 64 + cm) * EXS + cjb];
        f4 gG1 = *(const f4*)&sEx[(2 * 64 + cm) * EXS + cjb + 4];
        f4 gO0 = *(const f4*)&sEx[(3 * 64 + cm) * EXS + cjb];
        f4 gO1 = *(const f4*)&sEx[(3 * 64 + cm) * EXS + cjb + 4];
        _Float16 hi8[8], lo8[8];
        #pragma unroll
        for (int x = 0; x < 4; ++x) {
            float iv = sigm(gI0[x] + bi[0][x]);
            float fv = sigm(gF0[x] + bi[2][x]);
            float gv = tanh_(gG0[x] + bi[4][x]);
            float ov = sigm(gO0[x] + bi[6][x]);
            float cn = fv * cpre0[x] + iv * gv;
            float hn = ov * tanh_(cn);
            cpre0[x] = cn;
            _Float16 hi = (_Float16)hn;
            hi8[x] = hi;
            lo8[x] = (_Float16)(hn - (float)hi);
        }
        #pragma unroll
        for (int x = 0; x < 4; ++x) {
            float iv = sigm(gI1[x] + bi[1][x]);
            float fv = sigm(gF1[x] + bi[3][x]);
            float gv = tanh_(gG1[x] + bi[5][x]);
            float ov = sigm(gO1[x] + bi[7][x]);
            float cn = fv * cpre1[x] + iv * gv;
            float hn = ov * tanh_(cn);
            cpre1[x] = cn;
            _Float16 hi = (_Float16)hn;
            hi8[4 + x] = hi;
            lo8[4 + x] = (_Float16)(hn - (float)hi);
        }
        *(f4*)&cst[ccrow]     = cpre0;
        *(f4*)&cst[ccrow + 4] = cpre1;
        *(u32x4*)&hh_out[ccrow]        = *(u32x4*)hi8;
        *(u32x4*)&hl_out[ccrow]        = *(u32x4*)lo8;
        *(u32x4*)&sHh[cm * HSTR + cjb] = *(u32x4*)hi8;
        *(u32x4*)&sHl[cm * HSTR + cjb] = *(u32x4*)lo8;
    }
    __syncthreads();

    // ---- Delta partial: dl_out[s] = (h_hi+h_lo)(strip) @ Wout^T; wave wv -> out-cols wv*16.. ----
    {
        f4 d[4];
        #pragma unroll
        for (int a = 0; a < 4; ++a) d[a] = zero;
        #pragma unroll
        for (int a = 0; a < 4; ++a) {
            half8 ahh = *(const half8*)&sHh[(a * 16 + l15) * HSTR + quad8];
            half8 ahl = *(const half8*)&sHl[(a * 16 + l15) * HSTR + quad8];
            d[a] = __builtin_amdgcn_mfma_f32_16x16x32_f16(ahh, bw, d[a], 0, 0, 0);
            d[a] = __builtin_amdgcn_mfma_f32_16x16x32_f16(ahl, bw, d[a], 0, 0, 0);
        }
        #pragma unroll
        for (int a = 0; a < 4; ++a)
            #pragma unroll
            for (int r = 0; r < 4; ++r)
                dl_out[s * 65536 + (m0 + a * 16 + quad * 4 + r) * 64 + wv * 16 + l15] = d[a][r];
    }
}

// ---------------- host ----------------
extern "C" void kernel_launch(void* const* d_in, const int* in_sizes, int n_in,
                              void* d_out, int out_size, void* d_ws, size_t ws_size,
                              hipStream_t stream)
{
    const float* z   = (const float*)d_in[0];
    const float* x   = (const float*)d_in[1];
    const float* Wih = (const float*)d_in[2];
    const float* Whh = (const float*)d_in[3];
    const float* bih = (const float*)d_in[4];
    const float* bhh = (const float*)d_in[5];
    const float* Wp  = (const float*)d_in[6];
    const float* bp  = (const float*)d_in[7];
    const float* Wo  = (const float*)d_in[8];
    const float* bo  = (const float*)d_in[9];

    char* w = (char*)d_ws;
    _Float16* WA  = (_Float16*)w; w += 2359296;   // [2048][576] fp16
    _Float16* WB  = (_Float16*)w; w += 2359296;
    _Float16* WoB = (_Float16*)w; w += 65536;     // [64][512] fp16
    float* b0v = (float*)w; w += 8192;
    float* b1v = (float*)w; w += 8192;
    _Float16* hh[2];
    hh[0] = (_Float16*)w; w += 1048576;
    hh[1] = (_Float16*)w; w += 1048576;
    _Float16* hl[2];
    hl[0] = (_Float16*)w; w += 1048576;
    hl[1] = (_Float16*)w; w += 1048576;
    float* cst = (float*)w; w += 2097152;
    float* yf[2];
    yf[0] = (float*)w; w += 262144;
    yf[1] = (float*)w; w += 262144;
    _Float16* yh[2];
    yh[0] = (_Float16*)w; w += 131072;
    yh[1] = (_Float16*)w; w += 131072;
    _Float16* yl[2];
    yl[0] = (_Float16*)w; w += 131072;
    yl[1] = (_Float16*)w; w += 131072;
    float* dl[2];
    dl[0] = (float*)w; w += 4194304;              // [16][1024][64] fp32
    dl[1] = (float*)w; w += 4194304;
    float* out = (float*)d_out;

    k_wcat<<<4608, 256, 0, stream>>>(Wih, Whh, WA, WB);
    k_comb<<<4096, 256, 0, stream>>>(Wih, Whh, Wo, WB);
    k_misc<<<392, 256, 0, stream>>>(Wo, bih, bhh, Wih, bo, x, WoB, b0v, b1v,
                                    yf[0], yf[1], yh[0], yh[1], yl[0], yl[1]);
    k_h0<<<2048, 256, 0, stream>>>(z, Wp, bp, cst, hh[0], hl[0]);

    for (int t = 0; t <= 128; ++t) {
        k_step<<<256, 256, 0, stream>>>(t,
            (t == 0) ? WA : WB, (t == 0) ? b0v : b1v,
            WoB, bo,
            hh[t & 1], hl[t & 1], hh[(t + 1) & 1], hl[(t + 1) & 1],
            cst,
            yf[t & 1], yf[(t + 1) & 1],
            yh[t & 1], yh[(t + 1) & 1],
            yl[t & 1], yl[(t + 1) & 1],
            dl[(t + 1) & 1], dl[t & 1],
            out);
    }
}

// Round 9
// 2011.848 us; speedup vs baseline: 1.6090x; 1.6090x over previous
//
#include <hip/hip_runtime.h>
#include <stdint.h>

typedef _Float16 half8 __attribute__((ext_vector_type(8)));  // 8 fp16 (4 VGPR) MFMA frag
typedef __attribute__((ext_vector_type(4))) float f4;        // fp32x4 accum
typedef __attribute__((ext_vector_type(4))) unsigned int u32x4;
typedef __attribute__((ext_vector_type(2))) unsigned int u32x2;

#define LDAH 200   // halves per LDS A row (192 data + 8 pad; 25 x 16B slots, odd -> conflict-free b128)
#define EXS  34    // exchange stride (floats)
#define HSTR 40    // sH stride (halves), 80B: 16B-aligned

__device__ __forceinline__ float sigm(float x) { return 1.0f / (1.0f + __expf(-x)); }
__device__ __forceinline__ float tanh_(float x) { return 1.0f - 2.0f / (__expf(2.0f * x) + 1.0f); } // overflow-safe

// ---------------- prologue kernels ----------------

// W_catA[2048][576] = [W_ih | W_hh] fp16 ; also W_ih part of W_catB
extern "C" __global__ void __launch_bounds__(256) k_wcat(
    const float* __restrict__ Wih, const float* __restrict__ Whh,
    _Float16* __restrict__ WA, _Float16* __restrict__ WB)
{
    int idx = blockIdx.x * 256 + threadIdx.x;        // grid 4608 -> exactly 2048*576
    int n = idx / 576, k = idx % 576;
    float v = (k < 64) ? Wih[n * 64 + k] : Whh[n * 512 + (k - 64)];
    _Float16 b = (_Float16)v;
    WA[idx] = b;
    if (k < 64) WB[idx] = b;
}

// W_catB[n][64+k] = W_hh[n][k] + sum_p W_ih[n][p] * W_out[p][k]   (fp32 accum, fp16 store)
extern "C" __global__ void __launch_bounds__(256) k_comb(
    const float* __restrict__ Wih, const float* __restrict__ Whh,
    const float* __restrict__ Wo, _Float16* __restrict__ WB)
{
    int bx = blockIdx.x;                             // grid 4096
    int n = bx >> 1;
    int kh = ((bx & 1) << 8) + threadIdx.x;          // 0..511
    float acc = Whh[n * 512 + kh];
    #pragma unroll 16
    for (int p = 0; p < 64; ++p)
        acc += Wih[n * 64 + p] * Wo[p * 512 + kh];
    WB[n * 576 + 64 + kh] = (_Float16)acc;
}

// Wout fp16, bias0 = b_ih+b_hh, bias1 = bias0 + W_ih@b_out, y_{-1} init (fp32 + fp16 hi/lo, both parities)
extern "C" __global__ void __launch_bounds__(256) k_misc(
    const float* __restrict__ Wo, const float* __restrict__ bih, const float* __restrict__ bhh,
    const float* __restrict__ Wih, const float* __restrict__ bo, const float* __restrict__ x,
    _Float16* __restrict__ WoB, float* __restrict__ b0v, float* __restrict__ b1v,
    float* __restrict__ yf0, float* __restrict__ yf1,
    _Float16* __restrict__ yh0, _Float16* __restrict__ yh1,
    _Float16* __restrict__ yl0, _Float16* __restrict__ yl1)
{
    int idx = blockIdx.x * 256 + threadIdx.x;        // grid 392
    if (idx < 32768) { WoB[idx] = (_Float16)Wo[idx]; return; }
    if (idx < 34816) {
        int n = idx - 32768;
        float b = bih[n] + bhh[n];
        b0v[n] = b;
        float a = b;
        #pragma unroll 16
        for (int p = 0; p < 64; ++p) a += Wih[n * 64 + p] * bo[p];
        b1v[n] = a;
        return;
    }
    if (idx < 100352) {
        int e = idx - 34816;
        int m = e >> 6, nn = e & 63;
        float v = x[m * 2048 + 31 * 64 + nn];        // x[:, -1, :]
        yf0[e] = v; yf1[e] = v;
        _Float16 hi = (_Float16)v;
        _Float16 lo = (_Float16)(v - (float)hi);
        yh0[e] = hi; yh1[e] = hi;
        yl0[e] = lo; yl1[e] = lo;
    }
}

// h0 = z @ Wproj^T + b_proj ; c0 = h0 ; h stored fp16 hi/lo
extern "C" __global__ void __launch_bounds__(256) k_h0(
    const float* __restrict__ z, const float* __restrict__ Wp, const float* __restrict__ bp,
    float* __restrict__ cst, _Float16* __restrict__ hh0, _Float16* __restrict__ hl0)
{
    int bx = blockIdx.x;                             // grid 2048
    int m = bx >> 1;
    int n = ((bx & 1) << 8) + threadIdx.x;
    float acc = bp[n];
    const f4* zr = (const f4*)&z[m * 128];           // block-uniform (scalar loads)
    const f4* wr = (const f4*)&Wp[n * 128];
    #pragma unroll 8
    for (int p = 0; p < 32; ++p) {
        f4 zv = zr[p], wv = wr[p];
        acc += zv[0]*wv[0] + zv[1]*wv[1] + zv[2]*wv[2] + zv[3]*wv[3];
    }
    cst[m * 512 + n] = acc;
    _Float16 hi = (_Float16)acc;
    hh0[m * 512 + n] = hi;
    hl0[m * 512 + n] = (_Float16)(acc - (float)hi);
}

// ---------------- per-step kernel ----------------
// grid 256 = 16 mt x 16 s (R2 structure, 1994 us proven). ONE change vs R2: the A chunks
// are DOUBLE-BUFFERED in LDS. R2's schedule put __syncthreads (which the compiler precedes
// with s_waitcnt vmcnt(0)) between the prefetch issue and the MFMA phase -> the drain killed
// every prefetch. Here: issue loads for ch+1 -> MFMA on buf[cur] (~0.7us covers the loads)
// -> write buf[cur^1] (auto-waitcnt lands AFTER compute) -> one barrier. 8 barriers -> 6,
// and all three staging drains are hidden under MFMA. Everything else byte-identical to R2.
// LDS: 4 x 25.6 KB A-bufs + 10.2 KB H = 112.6 KB (1 block/CU; occupancy proven irrelevant).
// t in [0,128]; t==128 -> resolution of y_127 only.
extern "C" __global__ void __launch_bounds__(256, 1) k_step(
    int t,
    const _Float16* __restrict__ Wcat,         // [2048][576] fp16 (A or B variant)
    const float* __restrict__ bias,            // [2048]
    const _Float16* __restrict__ Wout,         // [64][512] fp16
    const float* __restrict__ bout,            // [64]
    const _Float16* __restrict__ hh_in, const _Float16* __restrict__ hl_in,  // [1024][512]
    _Float16* __restrict__ hh_out, _Float16* __restrict__ hl_out,
    float* __restrict__ cst,                   // [1024][512] fp32 (in-place)
    const float* __restrict__ yf_in, float* __restrict__ yf_out,             // [1024][64]
    const _Float16* __restrict__ yh_in, _Float16* __restrict__ yh_out,
    const _Float16* __restrict__ yl_in, _Float16* __restrict__ yl_out,
    const float* __restrict__ dl_in, float* __restrict__ dl_out,             // [16][1024][64]
    float* __restrict__ out)                   // [1024][128][64]
{
    __shared__ __align__(16) unsigned char smem[112640];
    _Float16* sAh0 = (_Float16*)smem;                            // [64][LDAH] = 25,600 B
    _Float16* sAl0 = (_Float16*)(smem + 25600);
    _Float16* sAh1 = (_Float16*)(smem + 51200);
    _Float16* sAl1 = (_Float16*)(smem + 76800);                  // ends 102,400
    float*    sEx  = (float*)smem;                               // overlay buf0: [4][64][EXS] = 34,816 B
    _Float16* sHh  = (_Float16*)(smem + 102400);                 // [64][HSTR] = 5,120 B
    _Float16* sHl  = (_Float16*)(smem + 107520);                 // 5,120 B (ends 112,640)
    _Float16* const sAh[2] = { sAh0, sAh1 };
    _Float16* const sAl[2] = { sAl0, sAl1 };

    const int tid = threadIdx.x;
    const int bx  = blockIdx.x;
    const int mt  = bx >> 4, s = bx & 15;
    const int m0  = mt * 64, j0 = s * 32;

    // ---- resolve y_{t-1} = y_{t-2} + b_out + sum_s Delta_{t-1,s} (4 rows per block) ----
    if (t >= 1 && tid < 64) {
        int row = m0 + s * 4 + (tid >> 4);
        int c4  = (tid & 15) * 4;
        f4 a = *(const f4*)&yf_in[row * 64 + c4];
        a += *(const f4*)&bout[c4];
        #pragma unroll
        for (int sp = 0; sp < 16; ++sp)
            a += *(const f4*)&dl_in[sp * 65536 + row * 64 + c4];
        *(f4*)&yf_out[row * 64 + c4] = a;
        *(f4*)&out[row * 8192 + (t - 1) * 64 + c4] = a;
        _Float16 hi4[4], lo4[4];
        #pragma unroll
        for (int x = 0; x < 4; ++x) {
            hi4[x] = (_Float16)a[x];
            lo4[x] = (_Float16)(a[x] - (float)hi4[x]);
        }
        *(u32x2*)&yh_out[row * 64 + c4] = *(u32x2*)hi4;
        *(u32x2*)&yl_out[row * 64 + c4] = *(u32x2*)lo4;
    }
    if (t >= 128) return;

    const int wv = tid >> 6, lane = tid & 63, l15 = lane & 15, quad = lane >> 4;
    const int quad8 = quad * 8;

    f4 zero = {0.0f, 0.0f, 0.0f, 0.0f};
    f4 acc[4][2];
    #pragma unroll
    for (int a = 0; a < 4; ++a) { acc[a][0] = zero; acc[a][1] = zero; }

    const int brow0 = (wv * 512 + j0 + l15) * 576;
    const int brow1 = (wv * 512 + j0 + 16 + l15) * 576;

    // ---- chunk-0 B prefetch (reg double-buffer, as R2) ----
    half8 bv0[2][6], bv1[2][6];
    #pragma unroll
    for (int kc = 0; kc < 6; ++kc) {
        bv0[0][kc] = *(const half8*)&Wcat[brow0 + kc * 32 + quad8];
        bv1[0][kc] = *(const half8*)&Wcat[brow1 + kc * 32 + quad8];
    }

    // per-thread staging coordinates (fixed across chunks): 6 x 16B x 2 streams, 64 rows x 192 halves
    int rr[6], cc6[6];
    #pragma unroll
    for (int it = 0; it < 6; ++it) {
        int i4 = it * 256 + tid;
        rr[it]  = i4 / 24;
        cc6[it] = (i4 % 24) * 8;
    }

    // ---- prologue: stage chunk 0 into buf0 (B-cols 0..191: y part + h[0..127]) ----
    #pragma unroll
    for (int it = 0; it < 6; ++it) {
        int r = rr[it], cc = cc6[it];
        const _Float16 *sh, *sl;
        if (cc < 64) { sh = &yh_in[(m0 + r) * 64 + cc];         sl = &yl_in[(m0 + r) * 64 + cc]; }
        else         { sh = &hh_in[(m0 + r) * 512 + (cc - 64)]; sl = &hl_in[(m0 + r) * 512 + (cc - 64)]; }
        *(u32x4*)&sAh0[r * LDAH + cc] = *(const u32x4*)sh;
        *(u32x4*)&sAl0[r * LDAH + cc] = *(const u32x4*)sl;
    }
    __syncthreads();                                 // the only exposed drain (chunk 0)

    // ---- 3 chunks; A LDS-double-buffered so the drain lands AFTER the MFMA phase ----
    u32x4 regH[6], regL[6];
    #pragma unroll
    for (int ch = 0; ch < 3; ++ch) {
        if (ch < 2) {
            #pragma unroll
            for (int it = 0; it < 6; ++it) {         // next chunk A (pure h stream)
                int c = (ch + 1) * 192 + cc6[it] - 64;
                regH[it] = *(const u32x4*)&hh_in[(m0 + rr[it]) * 512 + c];
                regL[it] = *(const u32x4*)&hl_in[(m0 + rr[it]) * 512 + c];
            }
            #pragma unroll
            for (int kc = 0; kc < 6; ++kc) {         // next chunk B
                bv0[(ch + 1) & 1][kc] = *(const half8*)&Wcat[brow0 + (ch + 1) * 192 + kc * 32 + quad8];
                bv1[(ch + 1) & 1][kc] = *(const half8*)&Wcat[brow1 + (ch + 1) * 192 + kc * 32 + quad8];
            }
        }
        // MFMA phase on buf[ch&1] — prefetch latency hides under this
        const _Float16* Ah = sAh[ch & 1];
        const _Float16* Al = sAl[ch & 1];
        #pragma unroll
        for (int kc = 0; kc < 6; ++kc) {
            int kq = kc * 32 + quad8;
            half8 b0 = bv0[ch & 1][kc], b1 = bv1[ch & 1][kc];
            half8 ah0 = *(const half8*)&Ah[(l15     ) * LDAH + kq];
            half8 ah1 = *(const half8*)&Ah[(l15 + 16) * LDAH + kq];
            half8 ah2 = *(const half8*)&Ah[(l15 + 32) * LDAH + kq];
            half8 ah3 = *(const half8*)&Ah[(l15 + 48) * LDAH + kq];
            acc[0][0] = __builtin_amdgcn_mfma_f32_16x16x32_f16(ah0, b0, acc[0][0], 0, 0, 0);
            acc[1][0] = __builtin_amdgcn_mfma_f32_16x16x32_f16(ah1, b0, acc[1][0], 0, 0, 0);
            acc[2][0] = __builtin_amdgcn_mfma_f32_16x16x32_f16(ah2, b0, acc[2][0], 0, 0, 0);
            acc[3][0] = __builtin_amdgcn_mfma_f32_16x16x32_f16(ah3, b0, acc[3][0], 0, 0, 0);
            acc[0][1] = __builtin_amdgcn_mfma_f32_16x16x32_f16(ah0, b1, acc[0][1], 0, 0, 0);
            acc[1][1] = __builtin_amdgcn_mfma_f32_16x16x32_f16(ah1, b1, acc[1][1], 0, 0, 0);
            acc[2][1] = __builtin_amdgcn_mfma_f32_16x16x32_f16(ah2, b1, acc[2][1], 0, 0, 0);
            acc[3][1] = __builtin_amdgcn_mfma_f32_16x16x32_f16(ah3, b1, acc[3][1], 0, 0, 0);
            half8 al0 = *(const half8*)&Al[(l15     ) * LDAH + kq];
            half8 al1 = *(const half8*)&Al[(l15 + 16) * LDAH + kq];
            half8 al2 = *(const half8*)&Al[(l15 + 32) * LDAH + kq];
            half8 al3 = *(const half8*)&Al[(l15 + 48) * LDAH + kq];
            acc[0][0] = __builtin_amdgcn_mfma_f32_16x16x32_f16(al0, b0, acc[0][0], 0, 0, 0);
            acc[1][0] = __builtin_amdgcn_mfma_f32_16x16x32_f16(al1, b0, acc[1][0], 0, 0, 0);
            acc[2][0] = __builtin_amdgcn_mfma_f32_16x16x32_f16(al2, b0, acc[2][0], 0, 0, 0);
            acc[3][0] = __builtin_amdgcn_mfma_f32_16x16x32_f16(al3, b0, acc[3][0], 0, 0, 0);
            acc[0][1] = __builtin_amdgcn_mfma_f32_16x16x32_f16(al0, b1, acc[0][1], 0, 0, 0);
            acc[1][1] = __builtin_amdgcn_mfma_f32_16x16x32_f16(al1, b1, acc[1][1], 0, 0, 0);
            acc[2][1] = __builtin_amdgcn_mfma_f32_16x16x32_f16(al2, b1, acc[2][1], 0, 0, 0);
            acc[3][1] = __builtin_amdgcn_mfma_f32_16x16x32_f16(al3, b1, acc[3][1], 0, 0, 0);
        }
        if (ch < 2) {
            // write NEXT chunk into the OTHER buffer: no WAR with this chunk's readers,
            // and the data-dependent waitcnt lands here, after the MFMA phase.
            _Float16* Dh = sAh[(ch + 1) & 1];
            _Float16* Dl = sAl[(ch + 1) & 1];
            #pragma unroll
            for (int it = 0; it < 6; ++it) {
                *(u32x4*)&Dh[rr[it] * LDAH + cc6[it]] = regH[it];
                *(u32x4*)&Dl[rr[it] * LDAH + cc6[it]] = regL[it];
            }
            __syncthreads();                         // writes visible before next chunk reads
        }
    }
    __syncthreads();                                 // all reads done -> overlay exchange

    // ---- gate exchange: wave wv = quadrant wv (i,f,g,o). D layout: col=lane&15, row=quad*4+reg ----
    #pragma unroll
    for (int a = 0; a < 4; ++a)
        #pragma unroll
        for (int b = 0; b < 2; ++b)
            #pragma unroll
            for (int r = 0; r < 4; ++r)
                sEx[(wv * 64 + a * 16 + quad * 4 + r) * EXS + b * 16 + l15] = acc[a][b][r];
    __syncthreads();

    // ---- LSTM cell update: thread -> row m, 8 h-cols ----
    {
        int m = tid >> 2, jb = (tid & 3) * 8;
        int jcol = j0 + jb;
        int crow = (m0 + m) * 512 + jcol;
        f4 c0 = *(const f4*)&cst[crow];
        f4 c1 = *(const f4*)&cst[crow + 4];
        _Float16 hi8[8], lo8[8];
        #pragma unroll
        for (int x = 0; x < 8; ++x) {
            float gi = sEx[(0 * 64 + m) * EXS + jb + x] + bias[       jcol + x];
            float gf = sEx[(1 * 64 + m) * EXS + jb + x] + bias[ 512 + jcol + x];
            float gg = sEx[(2 * 64 + m) * EXS + jb + x] + bias[1024 + jcol + x];
            float go = sEx[(3 * 64 + m) * EXS + jb + x] + bias[1536 + jcol + x];
            float iv = sigm(gi), fv = sigm(gf), gv = tanh_(gg), ov = sigm(go);
            float cold = (x < 4) ? c0[x] : c1[x - 4];
            float cn = fv * cold + iv * gv;
            float hn = ov * tanh_(cn);
            if (x < 4) c0[x] = cn; else c1[x - 4] = cn;
            _Float16 hi = (_Float16)hn;
            hi8[x] = hi;
            lo8[x] = (_Float16)(hn - (float)hi);
        }
        *(f4*)&cst[crow]     = c0;
        *(f4*)&cst[crow + 4] = c1;
        *(u32x4*)&hh_out[crow]       = *(u32x4*)hi8;
        *(u32x4*)&hl_out[crow]       = *(u32x4*)lo8;
        *(u32x4*)&sHh[m * HSTR + jb] = *(u32x4*)hi8;
        *(u32x4*)&sHl[m * HSTR + jb] = *(u32x4*)lo8;
    }
    __syncthreads();

    // ---- Delta partial: dl_out[s] = (h_hi+h_lo)(strip) @ Wout^T, K=32 per m-tile ----
    {
        half8 bw = *(const half8*)&Wout[(wv * 16 + l15) * 512 + j0 + quad8];
        f4 d[4];
        #pragma unroll
        for (int a = 0; a < 4; ++a) d[a] = zero;
        #pragma unroll
        for (int a = 0; a < 4; ++a) {
            half8 ahh = *(const half8*)&sHh[(a * 16 + l15) * HSTR + quad8];
            half8 ahl = *(const half8*)&sHl[(a * 16 + l15) * HSTR + quad8];
            d[a] = __builtin_amdgcn_mfma_f32_16x16x32_f16(ahh, bw, d[a], 0, 0, 0);
            d[a] = __builtin_amdgcn_mfma_f32_16x16x32_f16(ahl, bw, d[a], 0, 0, 0);
        }
        #pragma unroll
        for (int a = 0; a < 4; ++a)
            #pragma unroll
            for (int r = 0; r < 4; ++r)
                dl_out[s * 65536 + (m0 + a * 16 + quad * 4 + r) * 64 + wv * 16 + l15] = d[a][r];
    }
}

// ---------------- host ----------------
extern "C" void kernel_launch(void* const* d_in, const int* in_sizes, int n_in,
                              void* d_out, int out_size, void* d_ws, size_t ws_size,
                              hipStream_t stream)
{
    const float* z   = (const float*)d_in[0];
    const float* x   = (const float*)d_in[1];
    const float* Wih = (const float*)d_in[2];
    const float* Whh = (const float*)d_in[3];
    const float* bih = (const float*)d_in[4];
    const float* bhh = (const float*)d_in[5];
    const float* Wp  = (const float*)d_in[6];
    const float* bp  = (const float*)d_in[7];
    const float* Wo  = (const float*)d_in[8];
    const float* bo  = (const float*)d_in[9];

    char* w = (char*)d_ws;
    _Float16* WA  = (_Float16*)w; w += 2359296;   // [2048][576] fp16
    _Float16* WB  = (_Float16*)w; w += 2359296;
    _Float16* WoB = (_Float16*)w; w += 65536;     // [64][512] fp16
    float* b0v = (float*)w; w += 8192;
    float* b1v = (float*)w; w += 8192;
    _Float16* hh[2];
    hh[0] = (_Float16*)w; w += 1048576;
    hh[1] = (_Float16*)w; w += 1048576;
    _Float16* hl[2];
    hl[0] = (_Float16*)w; w += 1048576;
    hl[1] = (_Float16*)w; w += 1048576;
    float* cst = (float*)w; w += 2097152;
    float* yf[2];
    yf[0] = (float*)w; w += 262144;
    yf[1] = (float*)w; w += 262144;
    _Float16* yh[2];
    yh[0] = (_Float16*)w; w += 131072;
    yh[1] = (_Float16*)w; w += 131072;
    _Float16* yl[2];
    yl[0] = (_Float16*)w; w += 131072;
    yl[1] = (_Float16*)w; w += 131072;
    float* dl[2];
    dl[0] = (float*)w; w += 4194304;              // [16][1024][64] fp32
    dl[1] = (float*)w; w += 4194304;
    float* out = (float*)d_out;

    k_wcat<<<4608, 256, 0, stream>>>(Wih, Whh, WA, WB);
    k_comb<<<4096, 256, 0, stream>>>(Wih, Whh, Wo, WB);
    k_misc<<<392, 256, 0, stream>>>(Wo, bih, bhh, Wih, bo, x, WoB, b0v, b1v,
                                    yf[0], yf[1], yh[0], yh[1], yl[0], yl[1]);
    k_h0<<<2048, 256, 0, stream>>>(z, Wp, bp, cst, hh[0], hl[0]);

    for (int t = 0; t <= 128; ++t) {
        k_step<<<256, 256, 0, stream>>>(t,
            (t == 0) ? WA : WB, (t == 0) ? b0v : b1v,
            WoB, bo,
            hh[t & 1], hl[t & 1], hh[(t + 1) & 1], hl[(t + 1) & 1],
            cst,
            yf[t & 1], yf[(t + 1) & 1],
            yh[t & 1], yh[(t + 1) & 1],
            yl[t & 1], yl[(t + 1) & 1],
            dl[(t + 1) & 1], dl[t & 1],
            out);
    }
}